// Round 1
// baseline (9712.100 us; speedup 1.0000x reference)
//
#include <hip/hip_runtime.h>
#include <hip/hip_bf16.h>

#define B_   256
#define T_   512
#define H_   128
#define G3_  384
#define VEC_ 32   // H_/4 float4 per row

using bf16 = __hip_bfloat16;

__device__ __forceinline__ float sigmoid_f(float x) {
    return 1.0f / (1.0f + __expf(-x));
}
// tanh via exp; saturates correctly for large |x| (inf -> 1, 0 -> -1)
__device__ __forceinline__ float tanh_f(float x) {
    return 1.0f - 2.0f / (__expf(2.0f * x) + 1.0f);
}

__device__ __forceinline__ float ld_cvt(const float* p) { return *p; }
__device__ __forceinline__ float ld_cvt(const bf16* p)  { return __bfloat162float(*p); }
__device__ __forceinline__ void  st_cvt(float* p, float v) { *p = v; }
__device__ __forceinline__ void  st_cvt(bf16* p, float v)  { *p = __float2bfloat16(v); }

// 128-length dot: x from LDS (wave-uniform address -> broadcast, conflict-free),
// w resident in VGPRs (requires full unroll so indices are compile-time).
__device__ __forceinline__ float dot128(const float4* __restrict__ xv,
                                        const float4* __restrict__ w) {
    float a0 = 0.f, a1 = 0.f;
#pragma unroll
    for (int i = 0; i < VEC_; i += 2) {
        float4 x0 = xv[i], x1 = xv[i + 1];
        a0 = fmaf(x0.x, w[i].x, a0);
        a0 = fmaf(x0.y, w[i].y, a0);
        a0 = fmaf(x0.z, w[i].z, a0);
        a0 = fmaf(x0.w, w[i].w, a0);
        a1 = fmaf(x1.x, w[i + 1].x, a1);
        a1 = fmaf(x1.y, w[i + 1].y, a1);
        a1 = fmaf(x1.z, w[i + 1].z, a1);
        a1 = fmaf(x1.w, w[i + 1].w, a1);
    }
    return a0 + a1;
}

// ---------------------------------------------------------------------------
// gx GEMM: gx[m][j] = dot(X[m], W[j]) + bias[j], M x 384, K=128.
// Thread j holds W row j in registers; X rows staged to LDS, broadcast-read.
// GATHER=true: X row = emb[idx[m]] (fused embedding lookup, layer 0).
// ---------------------------------------------------------------------------
template<bool GATHER, typename GXT>
__global__ __launch_bounds__(G3_, 3)
void gx_gemm(const float* __restrict__ X,
             const int*   __restrict__ idx,
             const float* __restrict__ emb,
             const float* __restrict__ W,     // [384,128]
             const float* __restrict__ bias,  // [384]
             GXT*         __restrict__ gx,    // [M,384]
             int M)
{
    __shared__ __align__(16) float Xs[64][132];  // +4 pad: eases staging-write conflicts
    const int j = threadIdx.x;

    float4 w[VEC_];
    {
        const float4* wrow = (const float4*)(W + (size_t)j * H_);
#pragma unroll
        for (int i = 0; i < VEC_; i++) w[i] = wrow[i];
    }
    const float bj = bias[j];

    const int nchunks = (M + 63) >> 6;
    for (int chunk = blockIdx.x; chunk < nchunks; chunk += gridDim.x) {
        const int m0 = chunk << 6;
        const int nrows = min(64, M - m0);
        // stage: nrows*32 float4 over 384 threads, coalesced global reads
        for (int p = j; p < nrows * VEC_; p += G3_) {
            const int r = p >> 5, kq = p & 31;
            const float4* src;
            if (GATHER) src = (const float4*)(emb + (size_t)idx[m0 + r] * H_);
            else        src = (const float4*)(X + (size_t)(m0 + r) * H_);
            *(float4*)&Xs[r][kq * 4] = src[kq];
        }
        __syncthreads();
        for (int r = 0; r < nrows; r++) {
            const float acc = dot128((const float4*)&Xs[r][0], w);
            st_cvt(&gx[(size_t)(m0 + r) * G3_ + j], acc + bj);
        }
        __syncthreads();
    }
}

// ---------------------------------------------------------------------------
// GRU recurrence, one block per batch row (no cross-batch dependency, so no
// grid-wide sync needed). Thread j owns W_hh row j in registers; hidden state
// lives in LDS. Gate order (PyTorch): r, z, n.
//   r = sig(gx_r + gh_r); z = sig(gx_z + gh_z); n = tanh(gx_n + r*gh_n)
//   h' = (1-z)*n + z*h          (gx includes b_ih; gh includes b_hh)
// ---------------------------------------------------------------------------
template<typename GXT, bool STORE_H, bool FINAL>
__global__ __launch_bounds__(G3_, 2)
void gru_rec(const GXT*  __restrict__ gx,    // [B,T,384]
             const float* __restrict__ Whh,  // [384,128]
             const float* __restrict__ bhh,  // [384]
             float*       __restrict__ hseq, // [B,T,128] if STORE_H
             const float* __restrict__ fc_w, // [3,128] if FINAL
             const float* __restrict__ fc_b, // [3]     if FINAL
             float*       __restrict__ out)  // [B,3]   if FINAL
{
    __shared__ __align__(16) float hbuf[H_];
    __shared__ float s_rz[2 * H_];
    __shared__ float x_n[H_];
    __shared__ float h_n[H_];

    const int j = threadIdx.x;
    const int b = blockIdx.x;

    float4 w[VEC_];
    {
        const float4* wrow = (const float4*)(Whh + (size_t)j * H_);
#pragma unroll
        for (int i = 0; i < VEC_; i++) w[i] = wrow[i];
    }
    const float bj = bhh[j];

    if (j < H_) hbuf[j] = 0.0f;
    __syncthreads();

    const GXT* grow = gx + (size_t)b * T_ * G3_ + j;

    for (int t = 0; t < T_; t++) {
        const float gxv = ld_cvt(grow);   // issued early, consumed after the dot
        grow += G3_;

        const float ghb = dot128((const float4*)hbuf, w) + bj;

        if (j < 2 * H_) {
            s_rz[j] = gxv + ghb;          // r,z preactivations (sums are fine)
        } else {
            x_n[j - 2 * H_] = gxv;        // n-gate keeps x- and h-sides separate
            h_n[j - 2 * H_] = ghb;
        }
        __syncthreads();

        if (j < H_) {
            const float r = sigmoid_f(s_rz[j]);
            const float z = sigmoid_f(s_rz[j + H_]);
            const float n = tanh_f(x_n[j] + r * h_n[j]);
            const float hnew = (1.0f - z) * n + z * hbuf[j];
            hbuf[j] = hnew;
            if (STORE_H) hseq[((size_t)b * T_ + t) * H_ + j] = hnew;
        }
        __syncthreads();
    }

    if (FINAL) {
        if (j < H_) hbuf[j] = fmaxf(hbuf[j], 0.0f);  // relu(last hidden)
        __syncthreads();
        if (j < 3) {
            float acc = fc_b[j];
            const float* fw = fc_w + j * H_;
#pragma unroll
            for (int k = 0; k < H_; k++) acc = fmaf(hbuf[k], fw[k], acc);
            out[b * 3 + j] = acc;
        }
    }
}

// ---------------------------------------------------------------------------
extern "C" void kernel_launch(void* const* d_in, const int* in_sizes, int n_in,
                              void* d_out, int out_size, void* d_ws, size_t ws_size,
                              hipStream_t stream)
{
    const int*   x    = (const int*)  d_in[0];
    const float* emb  = (const float*)d_in[1];
    const float* W_ih = (const float*)d_in[2];  // [2,384,128]
    const float* W_hh = (const float*)d_in[3];  // [2,384,128]
    const float* b_ih = (const float*)d_in[4];  // [2,384]
    const float* b_hh = (const float*)d_in[5];  // [2,384]
    const float* fc_w = (const float*)d_in[6];  // [3,128]
    const float* fc_b = (const float*)d_in[7];  // [3]
    float* out = (float*)d_out;

    const int M = B_ * T_;                      // 131072 rows
    const size_t gx_f32 = (size_t)M * G3_ * sizeof(float);  // 201.3 MB
    const size_t h1_f32 = (size_t)M * H_  * sizeof(float);  //  67.1 MB

    dim3 ggx(512), bgx(G3_);   // 2 blocks/CU, 2048 chunks of 64 rows -> 4/block
    dim3 grec(B_), brec(G3_);  // 1 block per batch row

    if (ws_size >= gx_f32 + h1_f32) {
        // fp32 scratch path
        float* gx = (float*)d_ws;
        float* h1 = (float*)((char*)d_ws + gx_f32);
        hipLaunchKernelGGL((gx_gemm<true, float>), ggx, bgx, 0, stream,
                           nullptr, x, emb, W_ih, b_ih, gx, M);
        hipLaunchKernelGGL((gru_rec<float, true, false>), grec, brec, 0, stream,
                           gx, W_hh, b_hh, h1, nullptr, nullptr, nullptr);
        hipLaunchKernelGGL((gx_gemm<false, float>), ggx, bgx, 0, stream,
                           h1, nullptr, nullptr, W_ih + G3_ * H_, b_ih + G3_, gx, M);
        hipLaunchKernelGGL((gru_rec<float, false, true>), grec, brec, 0, stream,
                           gx, W_hh + G3_ * H_, b_hh + G3_, nullptr, fc_w, fc_b, out);
    } else {
        // bf16-gx fallback (100.7 MB + 67.1 MB) if workspace is small
        const size_t gx_bf = (size_t)M * G3_ * sizeof(bf16);
        bf16*  gx = (bf16*)d_ws;
        float* h1 = (float*)((char*)d_ws + gx_bf);
        hipLaunchKernelGGL((gx_gemm<true, bf16>), ggx, bgx, 0, stream,
                           nullptr, x, emb, W_ih, b_ih, gx, M);
        hipLaunchKernelGGL((gru_rec<bf16, true, false>), grec, brec, 0, stream,
                           gx, W_hh, b_hh, h1, nullptr, nullptr, nullptr);
        hipLaunchKernelGGL((gx_gemm<false, bf16>), ggx, bgx, 0, stream,
                           h1, nullptr, nullptr, W_ih + G3_ * H_, b_ih + G3_, gx, M);
        hipLaunchKernelGGL((gru_rec<bf16, false, true>), grec, brec, 0, stream,
                           gx, W_hh + G3_ * H_, b_hh + G3_, nullptr, fc_w, fc_b, out);
    }
}

// Round 2
// 1335.318 us; speedup vs baseline: 7.2732x; 7.2732x over previous
//
#include <hip/hip_runtime.h>
#include <hip/hip_bf16.h>

#define B_   256
#define T_   512
#define H_   128
#define G3_  384
#define VEC_ 32   // H_/4 float4 per row

// ---- tiled GEMM config ----
#define TM   128
#define TN   128
#define TK   32
#define LDA  132   // padded leading dim (floats); 132*4=528 B keeps b128 16B-aligned

__device__ __forceinline__ float sigmoid_f(float x) {
    return 1.0f / (1.0f + __expf(-x));
}
__device__ __forceinline__ float tanh_f(float x) {
    return 1.0f - 2.0f / (__expf(2.0f * x) + 1.0f);
}

// ---------------------------------------------------------------------------
// gx GEMM: gx[m][n] = dot(X[m], W[n]) + bias[n].  M x 384, K = 128.
// Classic register-tiled GEMM: 256 threads, 128x128 tile, K chunked by 32,
// double-buffered LDS, 8x8 micro-tile per thread (two 4-wide groups offset
// by 64 in each dim so LDS b128 reads are <=2 addresses/bank -> conflict-free).
// GATHER=true: X row = emb[idx[m]] (fused embedding lookup, layer 0).
// ---------------------------------------------------------------------------
template<bool GATHER>
__global__ __launch_bounds__(256, 2)
void gx_gemm(const float* __restrict__ X,
             const int*   __restrict__ idx,
             const float* __restrict__ emb,
             const float* __restrict__ W,     // [384,128] row-major (W[n][k])
             const float* __restrict__ bias,  // [384]
             float*       __restrict__ gx)    // [M,384]
{
    __shared__ __align__(16) float As[2][TK][LDA];  // As[buf][k][m] (transposed)
    __shared__ __align__(16) float Bs[2][TK][LDA];  // Bs[buf][k][n] = W[n0+n][kc+k]

    const int tid = threadIdx.x;
    const int tn  = tid & 15;   // n fast -> coalesced stores
    const int tm  = tid >> 4;   // 0..15
    const int n0  = blockIdx.x * TN;   // 0..2
    const int m0  = blockIdx.y * TM;   // 0..1023

    // staging: p = tid + 256*s (s=0..3); row r = p>>3 (0..127), quad q = p&7.
    // 256*s is a multiple of 8 -> q is constant = tid&7, r_s = (tid>>3) + 32*s.
    const int q  = tid & 7;
    const float* rowA[4];
    const float* rowB[4];
#pragma unroll
    for (int s = 0; s < 4; s++) {
        const int r = (tid >> 3) + 32 * s;
        rowA[s] = GATHER ? (emb + (size_t)idx[m0 + r] * H_)
                         : (X + (size_t)(m0 + r) * H_);
        rowB[s] = W + (size_t)(n0 + r) * H_;
    }

    float4 stA[4], stB[4];
    auto load_chunk = [&](int kc) {
#pragma unroll
        for (int s = 0; s < 4; s++) {
            stA[s] = *(const float4*)(rowA[s] + kc + q * 4);
            stB[s] = *(const float4*)(rowB[s] + kc + q * 4);
        }
    };
    auto store_chunk = [&](int buf) {
#pragma unroll
        for (int s = 0; s < 4; s++) {
            const int r = (tid >> 3) + 32 * s;
#pragma unroll
            for (int d = 0; d < 4; d++) {
                As[buf][q * 4 + d][r] = ((const float*)&stA[s])[d];
                Bs[buf][q * 4 + d][r] = ((const float*)&stB[s])[d];
            }
        }
    };

    float4 acc[2][2][4];  // [mg][ng][mi] over ni (float4)
#pragma unroll
    for (int a = 0; a < 2; a++)
#pragma unroll
        for (int b = 0; b < 2; b++)
#pragma unroll
            for (int c = 0; c < 4; c++) acc[a][b][c] = make_float4(0.f, 0.f, 0.f, 0.f);

    load_chunk(0);
    store_chunk(0);
    __syncthreads();

    for (int c = 0; c < 4; c++) {
        if (c < 3) load_chunk((c + 1) * TK);   // global -> regs (next chunk)
        const int buf = c & 1;
#pragma unroll 4
        for (int k = 0; k < TK; k++) {
            float4 a0 = *(const float4*)&As[buf][k][tm * 4];
            float4 a1 = *(const float4*)&As[buf][k][64 + tm * 4];
            float4 b0 = *(const float4*)&Bs[buf][k][tn * 4];
            float4 b1 = *(const float4*)&Bs[buf][k][64 + tn * 4];
            float4 av[2] = {a0, a1}, bv[2] = {b0, b1};
#pragma unroll
            for (int mg = 0; mg < 2; mg++)
#pragma unroll
                for (int mi = 0; mi < 4; mi++) {
                    const float am = ((const float*)&av[mg])[mi];
#pragma unroll
                    for (int ng = 0; ng < 2; ng++) {
                        acc[mg][ng][mi].x = fmaf(am, bv[ng].x, acc[mg][ng][mi].x);
                        acc[mg][ng][mi].y = fmaf(am, bv[ng].y, acc[mg][ng][mi].y);
                        acc[mg][ng][mi].z = fmaf(am, bv[ng].z, acc[mg][ng][mi].z);
                        acc[mg][ng][mi].w = fmaf(am, bv[ng].w, acc[mg][ng][mi].w);
                    }
                }
        }
        if (c < 3) {
            store_chunk(buf ^ 1);              // regs -> LDS (other buffer)
            __syncthreads();
        }
    }

    // epilogue: +bias, coalesced float4 stores (lanes tn contiguous in n)
    const float4 bb0 = *(const float4*)(bias + n0 + tn * 4);
    const float4 bb1 = *(const float4*)(bias + n0 + 64 + tn * 4);
#pragma unroll
    for (int mg = 0; mg < 2; mg++)
#pragma unroll
        for (int mi = 0; mi < 4; mi++) {
            const int m = m0 + mg * 64 + tm * 4 + mi;
            float* dst = gx + (size_t)m * G3_ + n0;
            float4 v0 = acc[mg][0][mi];
            v0.x += bb0.x; v0.y += bb0.y; v0.z += bb0.z; v0.w += bb0.w;
            float4 v1 = acc[mg][1][mi];
            v1.x += bb1.x; v1.y += bb1.y; v1.z += bb1.z; v1.w += bb1.w;
            *(float4*)(dst + tn * 4) = v0;
            *(float4*)(dst + 64 + tn * 4) = v1;
        }
}

// ---------------------------------------------------------------------------
// 128-dot with 4 independent accumulator chains (dep-chain 32x4cyc ~ 128cyc).
// x from LDS broadcast (wave-uniform addr), w resident in VGPRs.
// ---------------------------------------------------------------------------
__device__ __forceinline__ float dot128(const float4* __restrict__ xv,
                                        const float4* __restrict__ w) {
    float a0 = 0.f, a1 = 0.f, a2 = 0.f, a3 = 0.f;
#pragma unroll
    for (int i = 0; i < VEC_; i += 4) {
        float4 x0 = xv[i], x1 = xv[i + 1], x2 = xv[i + 2], x3 = xv[i + 3];
        a0 = fmaf(x0.x, w[i].x, a0);     a0 = fmaf(x0.y, w[i].y, a0);
        a0 = fmaf(x0.z, w[i].z, a0);     a0 = fmaf(x0.w, w[i].w, a0);
        a1 = fmaf(x1.x, w[i+1].x, a1);   a1 = fmaf(x1.y, w[i+1].y, a1);
        a1 = fmaf(x1.z, w[i+1].z, a1);   a1 = fmaf(x1.w, w[i+1].w, a1);
        a2 = fmaf(x2.x, w[i+2].x, a2);   a2 = fmaf(x2.y, w[i+2].y, a2);
        a2 = fmaf(x2.z, w[i+2].z, a2);   a2 = fmaf(x2.w, w[i+2].w, a2);
        a3 = fmaf(x3.x, w[i+3].x, a3);   a3 = fmaf(x3.y, w[i+3].y, a3);
        a3 = fmaf(x3.z, w[i+3].z, a3);   a3 = fmaf(x3.w, w[i+3].w, a3);
    }
    return (a0 + a1) + (a2 + a3);
}

// ---------------------------------------------------------------------------
// GRU recurrence, one block per batch row. Thread j owns W_hh row j in regs
// (384 threads, launch_bounds(.,2) -> 256-VGPR budget, w[] fits).
// gx for the next 4 steps is register-prefetched to cover HBM latency.
// Gate order (PyTorch): r, z, n.
// ---------------------------------------------------------------------------
template<bool STORE_H, bool FINAL>
__global__ __launch_bounds__(G3_, 2)
void gru_rec(const float* __restrict__ gx,   // [B,T,384]
             const float* __restrict__ Whh,  // [384,128]
             const float* __restrict__ bhh,  // [384]
             float*       __restrict__ hseq, // [B,T,128] if STORE_H
             const float* __restrict__ fc_w, // [3,128]  if FINAL
             const float* __restrict__ fc_b, // [3]      if FINAL
             float*       __restrict__ out)  // [B,3]    if FINAL
{
    __shared__ __align__(16) float hbuf[H_];
    __shared__ float s_rz[2 * H_];
    __shared__ float x_n[H_];
    __shared__ float h_n[H_];

    const int j = threadIdx.x;
    const int b = blockIdx.x;

    float4 w[VEC_];
    {
        const float4* wrow = (const float4*)(Whh + (size_t)j * H_);
#pragma unroll
        for (int i = 0; i < VEC_; i++) w[i] = wrow[i];
    }
    const float bj = bhh[j];

    if (j < H_) hbuf[j] = 0.0f;
    __syncthreads();

    const float* grow = gx + (size_t)b * T_ * G3_ + j;

    float gpre[4];
#pragma unroll
    for (int u = 0; u < 4; u++) gpre[u] = grow[u * G3_];

    for (int t0 = 0; t0 < T_; t0 += 4) {
        float gcur[4];
#pragma unroll
        for (int u = 0; u < 4; u++) gcur[u] = gpre[u];
        if (t0 + 4 < T_) {
#pragma unroll
            for (int u = 0; u < 4; u++) gpre[u] = grow[(t0 + 4 + u) * G3_];
        }
#pragma unroll
        for (int u = 0; u < 4; u++) {
            const int t = t0 + u;
            const float ghb = dot128((const float4*)hbuf, w) + bj;

            if (j < 2 * H_) {
                s_rz[j] = gcur[u] + ghb;     // r,z preactivations
            } else {
                x_n[j - 2 * H_] = gcur[u];   // n-gate: keep x/h sides separate
                h_n[j - 2 * H_] = ghb;
            }
            __syncthreads();

            if (j < H_) {
                const float r = sigmoid_f(s_rz[j]);
                const float z = sigmoid_f(s_rz[j + H_]);
                const float n = tanh_f(x_n[j] + r * h_n[j]);
                const float hnew = (1.0f - z) * n + z * hbuf[j];
                hbuf[j] = hnew;
                if (STORE_H) hseq[((size_t)b * T_ + t) * H_ + j] = hnew;
            }
            __syncthreads();
        }
    }

    if (FINAL) {
        if (j < H_) hbuf[j] = fmaxf(hbuf[j], 0.0f);  // relu(last hidden)
        __syncthreads();
        if (j < 3) {
            float acc = fc_b[j];
            const float* fw = fc_w + j * H_;
#pragma unroll
            for (int k = 0; k < H_; k++) acc = fmaf(hbuf[k], fw[k], acc);
            out[b * 3 + j] = acc;
        }
    }
}

// ---------------------------------------------------------------------------
extern "C" void kernel_launch(void* const* d_in, const int* in_sizes, int n_in,
                              void* d_out, int out_size, void* d_ws, size_t ws_size,
                              hipStream_t stream)
{
    const int*   x    = (const int*)  d_in[0];
    const float* emb  = (const float*)d_in[1];
    const float* W_ih = (const float*)d_in[2];  // [2,384,128]
    const float* W_hh = (const float*)d_in[3];  // [2,384,128]
    const float* b_ih = (const float*)d_in[4];  // [2,384]
    const float* b_hh = (const float*)d_in[5];  // [2,384]
    const float* fc_w = (const float*)d_in[6];  // [3,128]
    const float* fc_b = (const float*)d_in[7];  // [3]
    float* out = (float*)d_out;

    const int M = B_ * T_;                                   // 131072 rows
    const size_t gx_f32 = (size_t)M * G3_ * sizeof(float);   // 201.3 MB

    float* gx = (float*)d_ws;
    float* h1 = (float*)((char*)d_ws + gx_f32);              // 67.1 MB

    dim3 ggx(G3_ / TN, M / TM);   // (3, 1024)
    dim3 bgx(256);
    dim3 grec(B_), brec(G3_);

    hipLaunchKernelGGL((gx_gemm<true>), ggx, bgx, 0, stream,
                       nullptr, x, emb, W_ih, b_ih, gx);
    hipLaunchKernelGGL((gru_rec<true, false>), grec, brec, 0, stream,
                       gx, W_hh, b_hh, h1, nullptr, nullptr, nullptr);
    hipLaunchKernelGGL((gx_gemm<false>), ggx, bgx, 0, stream,
                       h1, nullptr, nullptr, W_ih + G3_ * H_, b_ih + G3_, gx);
    hipLaunchKernelGGL((gru_rec<false, true>), grec, brec, 0, stream,
                       gx, W_hh + G3_ * H_, b_hh + G3_, nullptr, fc_w, fc_b, out);
}

// Round 3
// 1233.755 us; speedup vs baseline: 7.8720x; 1.0823x over previous
//
#include <hip/hip_runtime.h>
#include <hip/hip_bf16.h>

#define B_   256
#define T_   512
#define H_   128
#define G3_  384
#define VEC_ 32   // H_/4 float4 per row

// ---- tiled GEMM config ----
#define TM   128
#define TN   128
#define TK   32
#define LDA  132   // padded leading dim (floats); 132*4=528 B keeps b128 16B-aligned

__device__ __forceinline__ float sigmoid_f(float x) {
    return 1.0f / (1.0f + __expf(-x));
}
__device__ __forceinline__ float tanh_f(float x) {
    return 1.0f - 2.0f / (__expf(2.0f * x) + 1.0f);
}

// ---------------------------------------------------------------------------
// gx GEMM: gx[m][n] = dot(X[m], W[n]) + bias[n].  M x 384, K = 128.
// (unchanged from R2 — 128x128 tile, double-buffered LDS, 8x8 micro-tile)
// ---------------------------------------------------------------------------
template<bool GATHER>
__global__ __launch_bounds__(256, 2)
void gx_gemm(const float* __restrict__ X,
             const int*   __restrict__ idx,
             const float* __restrict__ emb,
             const float* __restrict__ W,     // [384,128] row-major (W[n][k])
             const float* __restrict__ bias,  // [384]
             float*       __restrict__ gx)    // [M,384]
{
    __shared__ __align__(16) float As[2][TK][LDA];
    __shared__ __align__(16) float Bs[2][TK][LDA];

    const int tid = threadIdx.x;
    const int tn  = tid & 15;
    const int tm  = tid >> 4;
    const int n0  = blockIdx.x * TN;
    const int m0  = blockIdx.y * TM;

    const int q  = tid & 7;
    const float* rowA[4];
    const float* rowB[4];
#pragma unroll
    for (int s = 0; s < 4; s++) {
        const int r = (tid >> 3) + 32 * s;
        rowA[s] = GATHER ? (emb + (size_t)idx[m0 + r] * H_)
                         : (X + (size_t)(m0 + r) * H_);
        rowB[s] = W + (size_t)(n0 + r) * H_;
    }

    float4 stA[4], stB[4];
    auto load_chunk = [&](int kc) {
#pragma unroll
        for (int s = 0; s < 4; s++) {
            stA[s] = *(const float4*)(rowA[s] + kc + q * 4);
            stB[s] = *(const float4*)(rowB[s] + kc + q * 4);
        }
    };
    auto store_chunk = [&](int buf) {
#pragma unroll
        for (int s = 0; s < 4; s++) {
            const int r = (tid >> 3) + 32 * s;
#pragma unroll
            for (int d = 0; d < 4; d++) {
                As[buf][q * 4 + d][r] = ((const float*)&stA[s])[d];
                Bs[buf][q * 4 + d][r] = ((const float*)&stB[s])[d];
            }
        }
    };

    float4 acc[2][2][4];
#pragma unroll
    for (int a = 0; a < 2; a++)
#pragma unroll
        for (int b = 0; b < 2; b++)
#pragma unroll
            for (int c = 0; c < 4; c++) acc[a][b][c] = make_float4(0.f, 0.f, 0.f, 0.f);

    load_chunk(0);
    store_chunk(0);
    __syncthreads();

    for (int c = 0; c < 4; c++) {
        if (c < 3) load_chunk((c + 1) * TK);
        const int buf = c & 1;
#pragma unroll 4
        for (int k = 0; k < TK; k++) {
            float4 a0 = *(const float4*)&As[buf][k][tm * 4];
            float4 a1 = *(const float4*)&As[buf][k][64 + tm * 4];
            float4 b0 = *(const float4*)&Bs[buf][k][tn * 4];
            float4 b1 = *(const float4*)&Bs[buf][k][64 + tn * 4];
            float4 av[2] = {a0, a1}, bv[2] = {b0, b1};
#pragma unroll
            for (int mg = 0; mg < 2; mg++)
#pragma unroll
                for (int mi = 0; mi < 4; mi++) {
                    const float am = ((const float*)&av[mg])[mi];
#pragma unroll
                    for (int ng = 0; ng < 2; ng++) {
                        acc[mg][ng][mi].x = fmaf(am, bv[ng].x, acc[mg][ng][mi].x);
                        acc[mg][ng][mi].y = fmaf(am, bv[ng].y, acc[mg][ng][mi].y);
                        acc[mg][ng][mi].z = fmaf(am, bv[ng].z, acc[mg][ng][mi].z);
                        acc[mg][ng][mi].w = fmaf(am, bv[ng].w, acc[mg][ng][mi].w);
                    }
                }
        }
        if (c < 3) {
            store_chunk(buf ^ 1);
            __syncthreads();
        }
    }

    const float4 bb0 = *(const float4*)(bias + n0 + tn * 4);
    const float4 bb1 = *(const float4*)(bias + n0 + 64 + tn * 4);
#pragma unroll
    for (int mg = 0; mg < 2; mg++)
#pragma unroll
        for (int mi = 0; mi < 4; mi++) {
            const int m = m0 + mg * 64 + tm * 4 + mi;
            float* dst = gx + (size_t)m * G3_ + n0;
            float4 v0 = acc[mg][0][mi];
            v0.x += bb0.x; v0.y += bb0.y; v0.z += bb0.z; v0.w += bb0.w;
            float4 v1 = acc[mg][1][mi];
            v1.x += bb1.x; v1.y += bb1.y; v1.z += bb1.z; v1.w += bb1.w;
            *(float4*)(dst + tn * 4) = v0;
            *(float4*)(dst + 64 + tn * 4) = v1;
        }
}

// ---------------------------------------------------------------------------
// GRU recurrence, one block per batch row. Thread j owns W_hh row j in regs.
// KEY FIX vs R2: the dot is inlined in the kernel body and w[] is only ever
// indexed by compile-time constants (no pointer escape) -> SROA keeps the
// 128-VGPR weight array register-resident (R2 passed w as const float4* to a
// helper -> SROA failed -> VGPR_Count=84 -> W_hh re-read from L2 every step,
// ~196 KB/CU/step = the 2390 cyc/step bottleneck).
// ---------------------------------------------------------------------------
template<bool STORE_H, bool FINAL>
__global__ __launch_bounds__(G3_, 2)
void gru_rec(const float* __restrict__ gx,   // [B,T,384]
             const float* __restrict__ Whh,  // [384,128]
             const float* __restrict__ bhh,  // [384]
             float*       __restrict__ hseq, // [B,T,128] if STORE_H
             const float* __restrict__ fc_w, // [3,128]  if FINAL
             const float* __restrict__ fc_b, // [3]      if FINAL
             float*       __restrict__ out)  // [B,3]    if FINAL
{
    __shared__ __align__(16) float hbuf[H_];
    __shared__ float s_rz[2 * H_];
    __shared__ float x_n[H_];
    __shared__ float h_n[H_];

    const int j = threadIdx.x;
    const int b = blockIdx.x;

    float4 w[VEC_];
    {
        const float4* wrow = (const float4*)(Whh + (size_t)j * H_);
#pragma unroll
        for (int i = 0; i < VEC_; i++) w[i] = wrow[i];
    }
    const float bj = bhh[j];

    if (j < H_) hbuf[j] = 0.0f;
    __syncthreads();

    const float* grow = gx + (size_t)b * T_ * G3_ + j;
    const float4* hv = (const float4*)hbuf;

    float gpre[4];
#pragma unroll
    for (int u = 0; u < 4; u++) gpre[u] = grow[u * G3_];

    for (int t0 = 0; t0 < T_; t0 += 4) {
        float gcur[4];
#pragma unroll
        for (int u = 0; u < 4; u++) gcur[u] = gpre[u];
        if (t0 + 4 < T_) {
#pragma unroll
            for (int u = 0; u < 4; u++) gpre[u] = grow[(t0 + 4 + u) * G3_];
        }
#pragma unroll
        for (int u = 0; u < 4; u++) {
            const int t = t0 + u;

            // ---- inlined 128-dot, 4 independent chains, w[] const-indexed ----
            float a0 = 0.f, a1 = 0.f, a2 = 0.f, a3 = 0.f;
#pragma unroll
            for (int i = 0; i < VEC_; i += 4) {
                float4 x0 = hv[i], x1 = hv[i + 1], x2 = hv[i + 2], x3 = hv[i + 3];
                a0 = fmaf(x0.x, w[i].x, a0);     a0 = fmaf(x0.y, w[i].y, a0);
                a0 = fmaf(x0.z, w[i].z, a0);     a0 = fmaf(x0.w, w[i].w, a0);
                a1 = fmaf(x1.x, w[i+1].x, a1);   a1 = fmaf(x1.y, w[i+1].y, a1);
                a1 = fmaf(x1.z, w[i+1].z, a1);   a1 = fmaf(x1.w, w[i+1].w, a1);
                a2 = fmaf(x2.x, w[i+2].x, a2);   a2 = fmaf(x2.y, w[i+2].y, a2);
                a2 = fmaf(x2.z, w[i+2].z, a2);   a2 = fmaf(x2.w, w[i+2].w, a2);
                a3 = fmaf(x3.x, w[i+3].x, a3);   a3 = fmaf(x3.y, w[i+3].y, a3);
                a3 = fmaf(x3.z, w[i+3].z, a3);   a3 = fmaf(x3.w, w[i+3].w, a3);
            }
            const float ghb = ((a0 + a1) + (a2 + a3)) + bj;

            if (j < 2 * H_) {
                s_rz[j] = gcur[u] + ghb;     // r,z preactivations
            } else {
                x_n[j - 2 * H_] = gcur[u];   // n-gate: keep x/h sides separate
                h_n[j - 2 * H_] = ghb;
            }
            __syncthreads();

            if (j < H_) {
                const float r = sigmoid_f(s_rz[j]);
                const float z = sigmoid_f(s_rz[j + H_]);
                const float n = tanh_f(x_n[j] + r * h_n[j]);
                const float hnew = (1.0f - z) * n + z * hbuf[j];
                hbuf[j] = hnew;
                if (STORE_H) hseq[((size_t)b * T_ + t) * H_ + j] = hnew;
            }
            __syncthreads();
        }
    }

    if (FINAL) {
        if (j < H_) hbuf[j] = fmaxf(hbuf[j], 0.0f);  // relu(last hidden)
        __syncthreads();
        if (j < 3) {
            float acc = fc_b[j];
            const float* fw = fc_w + j * H_;
#pragma unroll
            for (int k = 0; k < H_; k++) acc = fmaf(hbuf[k], fw[k], acc);
            out[b * 3 + j] = acc;
        }
    }
}

// ---------------------------------------------------------------------------
extern "C" void kernel_launch(void* const* d_in, const int* in_sizes, int n_in,
                              void* d_out, int out_size, void* d_ws, size_t ws_size,
                              hipStream_t stream)
{
    const int*   x    = (const int*)  d_in[0];
    const float* emb  = (const float*)d_in[1];
    const float* W_ih = (const float*)d_in[2];  // [2,384,128]
    const float* W_hh = (const float*)d_in[3];  // [2,384,128]
    const float* b_ih = (const float*)d_in[4];  // [2,384]
    const float* b_hh = (const float*)d_in[5];  // [2,384]
    const float* fc_w = (const float*)d_in[6];  // [3,128]
    const float* fc_b = (const float*)d_in[7];  // [3]
    float* out = (float*)d_out;

    const int M = B_ * T_;                                   // 131072 rows
    const size_t gx_f32 = (size_t)M * G3_ * sizeof(float);   // 201.3 MB

    float* gx = (float*)d_ws;
    float* h1 = (float*)((char*)d_ws + gx_f32);              // 67.1 MB

    dim3 ggx(G3_ / TN, M / TM);   // (3, 1024)
    dim3 bgx(256);
    dim3 grec(B_), brec(G3_);

    hipLaunchKernelGGL((gx_gemm<true>), ggx, bgx, 0, stream,
                       nullptr, x, emb, W_ih, b_ih, gx);
    hipLaunchKernelGGL((gru_rec<true, false>), grec, brec, 0, stream,
                       gx, W_hh, b_hh, h1, nullptr, nullptr, nullptr);
    hipLaunchKernelGGL((gx_gemm<false>), ggx, bgx, 0, stream,
                       h1, nullptr, nullptr, W_ih + G3_ * H_, b_ih + G3_, gx);
    hipLaunchKernelGGL((gru_rec<false, true>), grec, brec, 0, stream,
                       gx, W_hh + G3_ * H_, b_hh + G3_, nullptr, fc_w, fc_b, out);
}